// Round 1
// 511.560 us; speedup vs baseline: 1.0087x; 1.0087x over previous
//
#include <hip/hip_runtime.h>
#include <stdint.h>

#define AS1 __attribute__((address_space(1)))
#define AS3 __attribute__((address_space(3)))

typedef __bf16 bf16x8 __attribute__((ext_vector_type(8)));
typedef float f32x4 __attribute__((ext_vector_type(4)));

#if defined(__has_builtin)
#if __has_builtin(__builtin_amdgcn_global_load_lds)
#define USE_GLL 1
#else
#define USE_GLL 0
#endif
#else
#define USE_GLL 0
#endif

static __device__ __forceinline__ unsigned short f2bf(float f) {
    union { float f; uint32_t u; } v; v.f = f;
    uint32_t u = v.u + 0x7fffu + ((v.u >> 16) & 1u);
    return (unsigned short)(u >> 16);
}

// ---------------- elementwise prep ----------------
__global__ void k_f32_to_bf16(const float* __restrict__ in, unsigned short* __restrict__ out, int n) {
    int idx = (blockIdx.x * 256 + threadIdx.x) * 4;
    if (idx >= n) return;
    float4 v = *(const float4*)(in + idx);
    unsigned short r[4] = { f2bf(v.x), f2bf(v.y), f2bf(v.z), f2bf(v.w) };
    *(uint2*)(out + idx) = *(const uint2*)r;
}

// Acat sections (Bq,Bk,Bv,Bo contiguous) = U*diag(s_j) rows; Ub = plain bf16 basis.
__global__ void k_make_scaled(const float* __restrict__ basis,
                              const float* __restrict__ sq, const float* __restrict__ sk,
                              const float* __restrict__ sv, const float* __restrict__ so,
                              unsigned short* __restrict__ Bq, unsigned short* __restrict__ Bk,
                              unsigned short* __restrict__ Bv, unsigned short* __restrict__ Bo,
                              unsigned short* __restrict__ Ub) {
    int idx = blockIdx.x * 256 + threadIdx.x;
    int k = idx & 1023;
    float b = basis[idx];
    Bq[idx] = f2bf(b * sq[k]);
    Bk[idx] = f2bf(b * sk[k]);
    Bv[idx] = f2bf(b * sv[k]);
    Bo[idx] = f2bf(b * so[k]);
    Ub[idx] = f2bf(b);
}

// V^T: in [bh][2048][64] -> out [bh][64][2048]
__global__ void k_transpose_v(const unsigned short* __restrict__ vsb, unsigned short* __restrict__ vtb) {
    __shared__ __align__(16) unsigned short t[128 * 72];
    const int sc = blockIdx.x;   // s-chunk of 128
    const int bh = blockIdx.y;
    const int tid = threadIdx.x;
    #pragma unroll
    for (int rep = 0; rep < 4; ++rep) {
        int idx = rep * 256 + tid;          // 0..1023
        int s = idx >> 3, part = idx & 7;
        *(uint4*)(t + s * 72 + part * 8) =
            *(const uint4*)(vsb + ((size_t)bh * 2048 + sc * 128 + s) * 64 + part * 8);
    }
    __syncthreads();
    #pragma unroll
    for (int rep = 0; rep < 4; ++rep) {
        int idx = rep * 256 + tid;          // 0..1023
        int d = idx >> 4, pc = idx & 15;    // d row 0..63, 8-wide s chunk 0..15
        unsigned short tmp[8];
        #pragma unroll
        for (int j = 0; j < 8; ++j) tmp[j] = t[(pc * 8 + j) * 72 + d];
        *(uint4*)(vtb + ((size_t)bh * 64 + d) * 2048 + sc * 128 + pc * 8) = *(const uint4*)tmp;
    }
}

// ---------------- GEMM 128x128 (m97): C = A[M][K] @ B[N][K]^T, QKV epilogue ----------------
#define BK 32

__global__ __launch_bounds__(256, 2)
void k_gemm_qkv(const unsigned short* __restrict__ A,
                const unsigned short* __restrict__ B,
                unsigned short* __restrict__ qkv,   // 3 sections of 4M elements
                int M, int N, int K)
{
    __shared__ __align__(16) unsigned short As[128 * BK];
    __shared__ __align__(16) unsigned short Bs[128 * BK];

    const int tid  = threadIdx.x;
    const int lane = tid & 63;
    const int w    = tid >> 6;
    const int wm   = w & 1;
    const int wn   = w >> 1;
    const int bm   = blockIdx.y;
    const int bn   = blockIdx.x;
    const int fm   = lane & 15;
    const int quad = lane >> 4;
    const int fk   = quad * 8;
    const int srow = lane >> 2;
    const int spart= lane & 3;

    f32x4 zero4 = {0.f, 0.f, 0.f, 0.f};
    f32x4 acc[4][4];
    #pragma unroll
    for (int i = 0; i < 4; ++i)
        #pragma unroll
        for (int j = 0; j < 4; ++j) acc[i][j] = zero4;

    for (int k0 = 0; k0 < K; k0 += BK) {
        #pragma unroll
        for (int t = 0; t < 2; ++t) {
            int row = w * 32 + t * 16 + srow;
            const unsigned short* ga = A + (size_t)(bm * 128 + row) * K + k0 + spart * 8;
            const unsigned short* gb = B + (size_t)(bn * 128 + row) * K + k0 + spart * 8;
#if USE_GLL
            __builtin_amdgcn_global_load_lds((const void AS1*)ga, (void AS3*)(As + w * 1024 + t * 512), 16, 0, 0);
            __builtin_amdgcn_global_load_lds((const void AS1*)gb, (void AS3*)(Bs + w * 1024 + t * 512), 16, 0, 0);
#else
            *(uint4*)(As + w * 1024 + t * 512 + lane * 8) = *(const uint4*)ga;
            *(uint4*)(Bs + w * 1024 + t * 512 + lane * 8) = *(const uint4*)gb;
#endif
        }
        __syncthreads();
        bf16x8 af[4], bfr[4];
        #pragma unroll
        for (int i = 0; i < 4; ++i) af[i] = *(const bf16x8*)(As + (wm * 64 + i * 16 + fm) * BK + fk);
        #pragma unroll
        for (int j = 0; j < 4; ++j) bfr[j] = *(const bf16x8*)(Bs + (wn * 64 + j * 16 + fm) * BK + fk);
        #pragma unroll
        for (int i = 0; i < 4; ++i)
            #pragma unroll
            for (int j = 0; j < 4; ++j)
                acc[i][j] = __builtin_amdgcn_mfma_f32_16x16x32_bf16(af[i], bfr[j], acc[i][j], 0, 0, 0);
        __syncthreads();
    }

    #pragma unroll
    for (int i = 0; i < 4; ++i)
        #pragma unroll
        for (int j = 0; j < 4; ++j)
            #pragma unroll
            for (int r = 0; r < 4; ++r) {
                int row = bm * 128 + wm * 64 + i * 16 + quad * 4 + r;
                int col = bn * 128 + wn * 64 + j * 16 + fm;
                int sec = col >> 10, cc = col & 1023;
                int bb = row >> 11, s = row & 2047;
                int hh = cc >> 6,  d = cc & 63;
                qkv[((size_t)sec << 22) + (((size_t)(bb * 16 + hh)) * 2048 + s) * 64 + d] = f2bf(acc[i][j][r]);
            }
}

// ---------------- GEMM 128Mx64N tiles ----------------
// EPI: 0 = bf16 row-major, 2 = f32 row-major
template<int EPI>
__global__ __launch_bounds__(256, 2)
void k_gemm_n64(const unsigned short* __restrict__ A,
                const unsigned short* __restrict__ B,
                void* __restrict__ Cout,
                int M, int N, int K)
{
    __shared__ __align__(16) unsigned short As[128 * BK];
    __shared__ __align__(16) unsigned short Bs[64 * BK];

    const int tid  = threadIdx.x;
    const int lane = tid & 63;
    const int w    = tid >> 6;
    const int wm   = w & 1;
    const int wn   = w >> 1;
    const int bm   = blockIdx.y;
    const int bn   = blockIdx.x;
    const int fm   = lane & 15;
    const int quad = lane >> 4;
    const int fk   = quad * 8;
    const int srow = lane >> 2;
    const int spart= lane & 3;

    f32x4 zero4 = {0.f, 0.f, 0.f, 0.f};
    f32x4 acc[4][2];
    #pragma unroll
    for (int i = 0; i < 4; ++i)
        #pragma unroll
        for (int j = 0; j < 2; ++j) acc[i][j] = zero4;

    for (int k0 = 0; k0 < K; k0 += BK) {
        #pragma unroll
        for (int t = 0; t < 2; ++t) {
            int row = w * 32 + t * 16 + srow;
            const unsigned short* ga = A + (size_t)(bm * 128 + row) * K + k0 + spart * 8;
#if USE_GLL
            __builtin_amdgcn_global_load_lds((const void AS1*)ga, (void AS3*)(As + w * 1024 + t * 512), 16, 0, 0);
#else
            *(uint4*)(As + w * 1024 + t * 512 + lane * 8) = *(const uint4*)ga;
#endif
        }
        {
            const unsigned short* gb = B + (size_t)(bn * 64 + w * 16 + srow) * K + k0 + spart * 8;
#if USE_GLL
            __builtin_amdgcn_global_load_lds((const void AS1*)gb, (void AS3*)(Bs + w * 512), 16, 0, 0);
#else
            *(uint4*)(Bs + w * 512 + lane * 8) = *(const uint4*)gb;
#endif
        }
        __syncthreads();
        bf16x8 af[4], bfr[2];
        #pragma unroll
        for (int i = 0; i < 4; ++i) af[i] = *(const bf16x8*)(As + (wm * 64 + i * 16 + fm) * BK + fk);
        #pragma unroll
        for (int j = 0; j < 2; ++j) bfr[j] = *(const bf16x8*)(Bs + (wn * 32 + j * 16 + fm) * BK + fk);
        #pragma unroll
        for (int i = 0; i < 4; ++i)
            #pragma unroll
            for (int j = 0; j < 2; ++j)
                acc[i][j] = __builtin_amdgcn_mfma_f32_16x16x32_bf16(af[i], bfr[j], acc[i][j], 0, 0, 0);
        __syncthreads();
    }

    #pragma unroll
    for (int i = 0; i < 4; ++i)
        #pragma unroll
        for (int j = 0; j < 2; ++j)
            #pragma unroll
            for (int r = 0; r < 4; ++r) {
                int row = bm * 128 + wm * 64 + i * 16 + quad * 4 + r;
                int col = bn * 64 + wn * 32 + j * 16 + fm;
                if (EPI == 0) ((unsigned short*)Cout)[(size_t)row * N + col] = f2bf(acc[i][j][r]);
                else          ((float*)Cout)[(size_t)row * N + col] = acc[i][j][r];
            }
}

// ---------------- flash attention v4: 128 q-rows/block (32 per wave), b-paired bias reuse ----------------
// grid: (16 qt-tiles, 32 y) with y = h*2 + b  => the two batches reading bias[h] are
// adjacent in dispatch order -> second batch hits L3 instead of HBM.
// Each wave owns 32 q-rows (2 fragment groups) so the per-wave K/V LDS re-read
// amortizes over 2x the output work (halves LDS-unit cycles per unit work).
__global__ __launch_bounds__(256, 2)
void k_attn(const unsigned short* __restrict__ qs, const unsigned short* __restrict__ ks,
            const unsigned short* __restrict__ vt, const float* __restrict__ bias,
            unsigned short* __restrict__ out)
{
    const int qt = 15 - blockIdx.x;  // heavy (long-k) blocks dispatched first
    const int by = blockIdx.y;       // 0..31
    const int h  = by >> 1;
    const int b  = by & 1;
    const int bh = b * 16 + h;
    const size_t rowbase = (size_t)bh * 2048;

    const int tid  = threadIdx.x;
    const int lane = tid & 63;
    const int w    = tid >> 6;
    const int fm   = lane & 15;
    const int quad = lane >> 4;
    const int fk   = quad * 8;

    __shared__ __align__(16) unsigned short Ks[64 * 72];       // [key][d]
    __shared__ __align__(16) unsigned short Vt[64 * 72];       // [d][key]
    __shared__ __align__(16) unsigned short Ps[4][32 * 72];    // per-wave P (32 q-rows)

    const int q0 = qt * 128 + w * 32;   // wave's first q-row; groups at q0, q0+16

    bf16x8 qf[2][2];
    #pragma unroll
    for (int g = 0; g < 2; ++g)
        #pragma unroll
        for (int c = 0; c < 2; ++c)
            qf[g][c] = *(const bf16x8*)(qs + (rowbase + q0 + g * 16 + fm) * 64 + c * 32 + fk);

    f32x4 zero4 = {0.f, 0.f, 0.f, 0.f};
    f32x4 oacc[2][4];
    float lsum[2][4];
    #pragma unroll
    for (int g = 0; g < 2; ++g) {
        #pragma unroll
        for (int jd = 0; jd < 4; ++jd) oacc[g][jd] = zero4;
        #pragma unroll
        for (int r = 0; r < 4; ++r) lsum[g][r] = 0.f;
    }

    const int nkt = qt * 2 + 2;
    for (int kt = 0; kt < nkt; ++kt) {
        // bias loads issued first: long-latency global reads overlap the staging below
        float bb[2][4][4];
        #pragma unroll
        for (int g = 0; g < 2; ++g)
            #pragma unroll
            for (int jn = 0; jn < 4; ++jn)
                #pragma unroll
                for (int r = 0; r < 4; ++r)
                    bb[g][jn][r] = bias[((size_t)h * 2048 + q0 + g * 16 + quad * 4 + r) * 2048
                                        + kt * 64 + jn * 16 + fm];

        #pragma unroll
        for (int rep = 0; rep < 2; ++rep) {
            int idx  = rep * 256 + tid;
            int row  = idx >> 3;
            int part = idx & 7;
            *(uint4*)(Ks + row * 72 + part * 8) =
                *(const uint4*)(ks + (rowbase + kt * 64 + row) * 64 + part * 8);
            *(uint4*)(Vt + row * 72 + part * 8) =
                *(const uint4*)(vt + ((size_t)bh * 64 + row) * 2048 + kt * 64 + part * 8);
        }
        __syncthreads();

        // QK^T: K-tile read ONCE per wave, feeds both 16-row groups
        bf16x8 kb[4][2];
        #pragma unroll
        for (int jn = 0; jn < 4; ++jn)
            #pragma unroll
            for (int c = 0; c < 2; ++c)
                kb[jn][c] = *(const bf16x8*)(Ks + (jn * 16 + fm) * 72 + c * 32 + fk);
        f32x4 sacc[2][4];
        #pragma unroll
        for (int g = 0; g < 2; ++g)
            #pragma unroll
            for (int jn = 0; jn < 4; ++jn) sacc[g][jn] = zero4;
        #pragma unroll
        for (int g = 0; g < 2; ++g)
            #pragma unroll
            for (int jn = 0; jn < 4; ++jn)
                #pragma unroll
                for (int c = 0; c < 2; ++c)
                    sacc[g][jn] = __builtin_amdgcn_mfma_f32_16x16x32_bf16(qf[g][c], kb[jn][c], sacc[g][jn], 0, 0, 0);

        #pragma unroll
        for (int g = 0; g < 2; ++g)
            #pragma unroll
            for (int jn = 0; jn < 4; ++jn)
                #pragma unroll
                for (int r = 0; r < 4; ++r) {
                    int row = q0 + g * 16 + quad * 4 + r;
                    int col = kt * 64 + jn * 16 + fm;
                    float p = exp2f(sacc[g][jn][r] * 0.18033688f + bb[g][jn][r] * 1.44269504f);
                    p = (col > row) ? 0.f : p;
                    lsum[g][r] += p;
                    Ps[w][(g * 16 + quad * 4 + r) * 72 + jn * 16 + fm] = f2bf(p);
                }

        // PV: V-tile read ONCE per wave, feeds both groups
        bf16x8 vf[4][2], pf[2][2];
        #pragma unroll
        for (int jd = 0; jd < 4; ++jd)
            #pragma unroll
            for (int c = 0; c < 2; ++c)
                vf[jd][c] = *(const bf16x8*)(Vt + (jd * 16 + fm) * 72 + c * 32 + fk);
        #pragma unroll
        for (int g = 0; g < 2; ++g)
            #pragma unroll
            for (int c = 0; c < 2; ++c)
                pf[g][c] = *(const bf16x8*)(Ps[w] + (g * 16 + fm) * 72 + c * 32 + fk);
        #pragma unroll
        for (int g = 0; g < 2; ++g)
            #pragma unroll
            for (int jd = 0; jd < 4; ++jd)
                #pragma unroll
                for (int c = 0; c < 2; ++c)
                    oacc[g][jd] = __builtin_amdgcn_mfma_f32_16x16x32_bf16(pf[g][c], vf[jd][c], oacc[g][jd], 0, 0, 0);

        __syncthreads();
    }

    #pragma unroll
    for (int g = 0; g < 2; ++g)
        #pragma unroll
        for (int r = 0; r < 4; ++r) {
            float l = lsum[g][r];
            #pragma unroll
            for (int off = 1; off < 16; off <<= 1) l += __shfl_xor(l, off, 64);
            lsum[g][r] = 1.f / l;
        }

    #pragma unroll
    for (int g = 0; g < 2; ++g)
        #pragma unroll
        for (int jd = 0; jd < 4; ++jd)
            #pragma unroll
            for (int r = 0; r < 4; ++r) {
                int row = q0 + g * 16 + quad * 4 + r;
                int d   = jd * 16 + fm;
                out[((size_t)b * 2048 + row) * 1024 + h * 64 + d] = f2bf(oacc[g][jd][r] * lsum[g][r]);
            }
}

// ---------------- launcher ----------------
extern "C" void kernel_launch(void* const* d_in, const int* in_sizes, int n_in,
                              void* d_out, int out_size, void* d_ws, size_t ws_size,
                              hipStream_t stream) {
    (void)in_sizes; (void)n_in; (void)out_size; (void)ws_size;
    const float* x     = (const float*)d_in[0];
    const float* basis = (const float*)d_in[1];
    const float* sq    = (const float*)d_in[2];
    const float* sk    = (const float*)d_in[3];
    const float* sv    = (const float*)d_in[4];
    const float* so    = (const float*)d_in[5];
    const float* bias  = (const float*)d_in[6];
    float* out = (float*)d_out;

    char* ws = (char*)d_ws;
    size_t off = 0;
    auto alloc = [&](size_t bytes) { void* p = ws + off; off += bytes; return p; };
    unsigned short* x_bf  = (unsigned short*)alloc((size_t)8 << 20);
    unsigned short* Acat  = (unsigned short*)alloc((size_t)8 << 20);   // [U*sq; U*sk; U*sv; U*so]
    unsigned short* Ub    = (unsigned short*)alloc((size_t)2 << 20);
    unsigned short* Wall  = (unsigned short*)alloc((size_t)8 << 20);   // [Wq; Wk; Wv; Wo] (each symmetric)
    unsigned short* qkvb  = (unsigned short*)alloc((size_t)24 << 20);  // q,k,v head-split sections
    unsigned short* vtb   = (unsigned short*)alloc((size_t)8 << 20);
    unsigned short* attno = (unsigned short*)alloc((size_t)8 << 20);

    unsigned short* Bq  = Acat;
    unsigned short* Bk  = Acat + ((size_t)1 << 20);
    unsigned short* Bv  = Acat + ((size_t)2 << 20);
    unsigned short* Bo  = Acat + ((size_t)3 << 20);
    unsigned short* qsb = qkvb;
    unsigned short* ksb = qkvb + ((size_t)1 << 22);
    unsigned short* vsb = qkvb + ((size_t)2 << 22);
    unsigned short* Wo  = Wall + (size_t)3 * 1024 * 1024;

    k_f32_to_bf16<<<4096, 256, 0, stream>>>(x, x_bf, 4096 * 1024);
    k_make_scaled<<<4096, 256, 0, stream>>>(basis, sq, sk, sv, so, Bq, Bk, Bv, Bo, Ub);

    dim3 blk(256);
    // Wall = Acat @ Ub^T   (W_j = U diag(s_j) U^T, symmetric => rows usable as B^T later)
    k_gemm_n64<0><<<dim3(16, 32), blk, 0, stream>>>(Acat, Ub, Wall, 4096, 1024, 1024);
    // QKV = x @ [Wq;Wk;Wv]^T  (symmetry: B rows = W rows)
    k_gemm_qkv<<<dim3(24, 32), blk, 0, stream>>>(x_bf, Wall, qkvb, 4096, 3072, 1024);
    k_transpose_v<<<dim3(16, 32), blk, 0, stream>>>(vsb, vtb);
    k_attn<<<dim3(16, 32), blk, 0, stream>>>(qsb, ksb, vtb, bias, attno);
    // out = attno @ Wo^T (f32 epilogue)
    k_gemm_n64<2><<<dim3(16, 32), blk, 0, stream>>>(attno, Wo, out, 4096, 1024, 1024);
}

// Round 2
// 510.496 us; speedup vs baseline: 1.0108x; 1.0021x over previous
//
#include <hip/hip_runtime.h>
#include <stdint.h>

#define AS1 __attribute__((address_space(1)))
#define AS3 __attribute__((address_space(3)))

typedef __bf16 bf16x8 __attribute__((ext_vector_type(8)));
typedef float f32x4 __attribute__((ext_vector_type(4)));

#if defined(__has_builtin)
#if __has_builtin(__builtin_amdgcn_global_load_lds)
#define USE_GLL 1
#else
#define USE_GLL 0
#endif
#else
#define USE_GLL 0
#endif

static __device__ __forceinline__ unsigned short f2bf(float f) {
    union { float f; uint32_t u; } v; v.f = f;
    uint32_t u = v.u + 0x7fffu + ((v.u >> 16) & 1u);
    return (unsigned short)(u >> 16);
}

// ---------------- fused elementwise prep ----------------
// blocks [0,4096): make scaled basis sections + Ub  (1M elements)
// blocks [4096,8192): x f32 -> bf16 (4M elements, float4 per thread)
__global__ void k_prep(const float* __restrict__ x, const float* __restrict__ basis,
                       const float* __restrict__ sq, const float* __restrict__ sk,
                       const float* __restrict__ sv, const float* __restrict__ so,
                       unsigned short* __restrict__ x_bf,
                       unsigned short* __restrict__ Bq, unsigned short* __restrict__ Bk,
                       unsigned short* __restrict__ Bv, unsigned short* __restrict__ Bo,
                       unsigned short* __restrict__ Ub) {
    int b = blockIdx.x;
    if (b < 4096) {
        int idx = b * 256 + threadIdx.x;
        int k = idx & 1023;
        float v = basis[idx];
        Bq[idx] = f2bf(v * sq[k]);
        Bk[idx] = f2bf(v * sk[k]);
        Bv[idx] = f2bf(v * sv[k]);
        Bo[idx] = f2bf(v * so[k]);
        Ub[idx] = f2bf(v);
    } else {
        int idx = ((b - 4096) * 256 + threadIdx.x) * 4;
        float4 v = *(const float4*)(x + idx);
        unsigned short r[4] = { f2bf(v.x), f2bf(v.y), f2bf(v.z), f2bf(v.w) };
        *(uint2*)(x_bf + idx) = *(const uint2*)r;
    }
}

// V^T: in [bh][2048][64] -> out [bh][64][2048]
__global__ void k_transpose_v(const unsigned short* __restrict__ vsb, unsigned short* __restrict__ vtb) {
    __shared__ __align__(16) unsigned short t[128 * 72];
    const int sc = blockIdx.x;   // s-chunk of 128
    const int bh = blockIdx.y;
    const int tid = threadIdx.x;
    #pragma unroll
    for (int rep = 0; rep < 4; ++rep) {
        int idx = rep * 256 + tid;          // 0..1023
        int s = idx >> 3, part = idx & 7;
        *(uint4*)(t + s * 72 + part * 8) =
            *(const uint4*)(vsb + ((size_t)bh * 2048 + sc * 128 + s) * 64 + part * 8);
    }
    __syncthreads();
    #pragma unroll
    for (int rep = 0; rep < 4; ++rep) {
        int idx = rep * 256 + tid;          // 0..1023
        int d = idx >> 4, pc = idx & 15;    // d row 0..63, 8-wide s chunk 0..15
        unsigned short tmp[8];
        #pragma unroll
        for (int j = 0; j < 8; ++j) tmp[j] = t[(pc * 8 + j) * 72 + d];
        *(uint4*)(vtb + ((size_t)bh * 64 + d) * 2048 + sc * 128 + pc * 8) = *(const uint4*)tmp;
    }
}

// ---------------- GEMM 256x256 deep-pipeline (counted vmcnt, 3-buf), QKV epilogue ----------
// C = A[4096][1024] @ B[3072][1024]^T.  512 thr (8 waves, 2M x 4N), BK=32, 32 K-tiles.
// Triple-buffered LDS: tile t reads buf[t%3] while staging tile t+2 into buf[(t+2)%3].
// Per wave per K-tile: 4 GLL stage instrs; single s_waitcnt vmcnt(4) per tile drains
// exactly tile t+1's stages while t+2's stay in flight (never vmcnt(0) in main loop).
// Raw s_barrier (NOT __syncthreads, which emits the vmcnt(0) drain).
__global__ __launch_bounds__(512, 2)
void k_gemm_qkv8(const unsigned short* __restrict__ A,
                 const unsigned short* __restrict__ B,
                 unsigned short* __restrict__ qkv)
{
    __shared__ __align__(16) unsigned short lds[3 * 16384];  // 96 KiB: per buf A[256][32] + B[256][32]

    const int tid  = threadIdx.x;
    const int lane = tid & 63;
    const int w    = tid >> 6;
    const int wm   = w & 1;     // M-half
    const int wn   = w >> 1;    // N-quarter
    const int fm   = lane & 15;
    const int quad = lane >> 4;
    const int K    = 1024;
    const int NT   = 32;

    // XCD-aware bijective swizzle over 192 blocks (24 contiguous per XCD)
    int bid  = blockIdx.y * 12 + blockIdx.x;
    int sbid = (bid & 7) * 24 + (bid >> 3);
    const int bm = sbid / 12;
    const int bn = sbid % 12;

    // staging coords: thread -> (row in half-tile, 16B granule)
    const int srow = tid >> 2;          // 0..127
    const int sg   = tid & 3;
    const unsigned short* gA = A + ((size_t)(bm * 256) + srow) * K + sg * 8;
    const unsigned short* gB = B + ((size_t)(bn * 256) + srow) * K + sg * 8;

#define STAGE_A8(tt, h) __builtin_amdgcn_global_load_lds( \
        (const void AS1*)(gA + (size_t)(h) * 128 * 1024 + (tt) * 32), \
        (void AS3*)(lds + ((tt) % 3) * 16384 + (h) * 4096 + w * 512), 16, 0, 0)
#define STAGE_B8(tt, h) __builtin_amdgcn_global_load_lds( \
        (const void AS1*)(gB + (size_t)(h) * 128 * 1024 + (tt) * 32), \
        (void AS3*)(lds + ((tt) % 3) * 16384 + 8192 + (h) * 4096 + w * 512), 16, 0, 0)

    f32x4 zero4 = {0.f, 0.f, 0.f, 0.f};
    f32x4 acc[8][4];
    #pragma unroll
    for (int i = 0; i < 8; ++i)
        #pragma unroll
        for (int j = 0; j < 4; ++j) acc[i][j] = zero4;

    // prologue: stage tiles 0 and 1, drain tile 0 only (keep tile 1 in flight)
    STAGE_A8(0, 0); STAGE_A8(0, 1); STAGE_B8(0, 0); STAGE_B8(0, 1);
    STAGE_A8(1, 0); STAGE_A8(1, 1); STAGE_B8(1, 0); STAGE_B8(1, 1);
    asm volatile("s_waitcnt vmcnt(4)" ::: "memory");
    __builtin_amdgcn_s_barrier();

    for (int t = 0; t < NT; ++t) {
        const unsigned short* buf = lds + (t % 3) * 16384;

        // ---- phase A: B-frags + A-frags 0-3, stage A-halves of t+2 ----
        bf16x8 bfr[4], af[4];
        #pragma unroll
        for (int j = 0; j < 4; ++j)
            bfr[j] = *(const bf16x8*)(buf + 8192 + (wn * 64 + j * 16 + fm) * 32 + quad * 8);
        #pragma unroll
        for (int i = 0; i < 4; ++i)
            af[i] = *(const bf16x8*)(buf + (wm * 128 + i * 16 + fm) * 32 + quad * 8);
        if (t + 2 < NT) { STAGE_A8(t + 2, 0); STAGE_A8(t + 2, 1); }
        __builtin_amdgcn_s_barrier();
        asm volatile("s_waitcnt lgkmcnt(0)" ::: "memory");
        __builtin_amdgcn_s_setprio(1);
        #pragma unroll
        for (int i = 0; i < 4; ++i)
            #pragma unroll
            for (int j = 0; j < 4; ++j)
                acc[i][j] = __builtin_amdgcn_mfma_f32_16x16x32_bf16(af[i], bfr[j], acc[i][j], 0, 0, 0);
        __builtin_amdgcn_s_setprio(0);
        __builtin_amdgcn_s_barrier();

        // ---- phase B: A-frags 4-7 (B reused in regs), stage B-halves of t+2 ----
        bf16x8 af2[4];
        #pragma unroll
        for (int i = 0; i < 4; ++i)
            af2[i] = *(const bf16x8*)(buf + (wm * 128 + 64 + i * 16 + fm) * 32 + quad * 8);
        if (t + 2 < NT) { STAGE_B8(t + 2, 0); STAGE_B8(t + 2, 1); }
        // counted drain: outstanding = 4 (tile t+1) + 4 (tile t+2) -> wait to 4
        if (t < NT - 2)       asm volatile("s_waitcnt vmcnt(4)" ::: "memory");
        else if (t == NT - 2) asm volatile("s_waitcnt vmcnt(0)" ::: "memory");
        __builtin_amdgcn_s_barrier();
        asm volatile("s_waitcnt lgkmcnt(0)" ::: "memory");
        __builtin_amdgcn_s_setprio(1);
        #pragma unroll
        for (int i = 0; i < 4; ++i)
            #pragma unroll
            for (int j = 0; j < 4; ++j)
                acc[i + 4][j] = __builtin_amdgcn_mfma_f32_16x16x32_bf16(af2[i], bfr[j], acc[i + 4][j], 0, 0, 0);
        __builtin_amdgcn_s_setprio(0);
        __builtin_amdgcn_s_barrier();
    }
#undef STAGE_A8
#undef STAGE_B8

    // epilogue: head-split scatter into q/k/v sections
    #pragma unroll
    for (int i = 0; i < 8; ++i)
        #pragma unroll
        for (int j = 0; j < 4; ++j)
            #pragma unroll
            for (int r = 0; r < 4; ++r) {
                int row = bm * 256 + wm * 128 + i * 16 + quad * 4 + r;
                int col = bn * 256 + wn * 64 + j * 16 + fm;
                int sec = col >> 10, cc = col & 1023;
                int bb = row >> 11, s = row & 2047;
                int hh = cc >> 6,  d = cc & 63;
                qkv[((size_t)sec << 22) + (((size_t)(bb * 16 + hh)) * 2048 + s) * 64 + d] = f2bf(acc[i][j][r]);
            }
}

// ---------------- GEMM 128Mx64N tiles ----------------
#define BK 32
// EPI: 0 = bf16 row-major, 2 = f32 row-major
template<int EPI>
__global__ __launch_bounds__(256, 2)
void k_gemm_n64(const unsigned short* __restrict__ A,
                const unsigned short* __restrict__ B,
                void* __restrict__ Cout,
                int M, int N, int K)
{
    __shared__ __align__(16) unsigned short As[128 * BK];
    __shared__ __align__(16) unsigned short Bs[64 * BK];

    const int tid  = threadIdx.x;
    const int lane = tid & 63;
    const int w    = tid >> 6;
    const int wm   = w & 1;
    const int wn   = w >> 1;
    const int bm   = blockIdx.y;
    const int bn   = blockIdx.x;
    const int fm   = lane & 15;
    const int quad = lane >> 4;
    const int fk   = quad * 8;
    const int srow = lane >> 2;
    const int spart= lane & 3;

    f32x4 zero4 = {0.f, 0.f, 0.f, 0.f};
    f32x4 acc[4][2];
    #pragma unroll
    for (int i = 0; i < 4; ++i)
        #pragma unroll
        for (int j = 0; j < 2; ++j) acc[i][j] = zero4;

    for (int k0 = 0; k0 < K; k0 += BK) {
        #pragma unroll
        for (int t = 0; t < 2; ++t) {
            int row = w * 32 + t * 16 + srow;
            const unsigned short* ga = A + (size_t)(bm * 128 + row) * K + k0 + spart * 8;
#if USE_GLL
            __builtin_amdgcn_global_load_lds((const void AS1*)ga, (void AS3*)(As + w * 1024 + t * 512), 16, 0, 0);
#else
            *(uint4*)(As + w * 1024 + t * 512 + lane * 8) = *(const uint4*)ga;
#endif
        }
        {
            const unsigned short* gb = B + (size_t)(bn * 64 + w * 16 + srow) * K + k0 + spart * 8;
#if USE_GLL
            __builtin_amdgcn_global_load_lds((const void AS1*)gb, (void AS3*)(Bs + w * 512), 16, 0, 0);
#else
            *(uint4*)(Bs + w * 512 + lane * 8) = *(const uint4*)gb;
#endif
        }
        __syncthreads();
        bf16x8 af[4], bfr[2];
        #pragma unroll
        for (int i = 0; i < 4; ++i) af[i] = *(const bf16x8*)(As + (wm * 64 + i * 16 + fm) * BK + fk);
        #pragma unroll
        for (int j = 0; j < 2; ++j) bfr[j] = *(const bf16x8*)(Bs + (wn * 32 + j * 16 + fm) * BK + fk);
        #pragma unroll
        for (int i = 0; i < 4; ++i)
            #pragma unroll
            for (int j = 0; j < 2; ++j)
                acc[i][j] = __builtin_amdgcn_mfma_f32_16x16x32_bf16(af[i], bfr[j], acc[i][j], 0, 0, 0);
        __syncthreads();
    }

    #pragma unroll
    for (int i = 0; i < 4; ++i)
        #pragma unroll
        for (int j = 0; j < 2; ++j)
            #pragma unroll
            for (int r = 0; r < 4; ++r) {
                int row = bm * 128 + wm * 64 + i * 16 + quad * 4 + r;
                int col = bn * 64 + wn * 32 + j * 16 + fm;
                if (EPI == 0) ((unsigned short*)Cout)[(size_t)row * N + col] = f2bf(acc[i][j][r]);
                else          ((float*)Cout)[(size_t)row * N + col] = acc[i][j][r];
            }
}

// ---------------- flash attention: 128 q-rows/block (32 per wave), b-paired bias reuse ------
__global__ __launch_bounds__(256, 2)
void k_attn(const unsigned short* __restrict__ qs, const unsigned short* __restrict__ ks,
            const unsigned short* __restrict__ vt, const float* __restrict__ bias,
            unsigned short* __restrict__ out)
{
    const int qt = 15 - blockIdx.x;  // heavy (long-k) blocks dispatched first
    const int by = blockIdx.y;       // 0..31
    const int h  = by >> 1;
    const int b  = by & 1;
    const int bh = b * 16 + h;
    const size_t rowbase = (size_t)bh * 2048;

    const int tid  = threadIdx.x;
    const int lane = tid & 63;
    const int w    = tid >> 6;
    const int fm   = lane & 15;
    const int quad = lane >> 4;
    const int fk   = quad * 8;

    __shared__ __align__(16) unsigned short Ks[64 * 72];       // [key][d]
    __shared__ __align__(16) unsigned short Vt[64 * 72];       // [d][key]
    __shared__ __align__(16) unsigned short Ps[4][32 * 72];    // per-wave P (32 q-rows)

    const int q0 = qt * 128 + w * 32;   // wave's first q-row; groups at q0, q0+16

    bf16x8 qf[2][2];
    #pragma unroll
    for (int g = 0; g < 2; ++g)
        #pragma unroll
        for (int c = 0; c < 2; ++c)
            qf[g][c] = *(const bf16x8*)(qs + (rowbase + q0 + g * 16 + fm) * 64 + c * 32 + fk);

    f32x4 zero4 = {0.f, 0.f, 0.f, 0.f};
    f32x4 oacc[2][4];
    float lsum[2][4];
    #pragma unroll
    for (int g = 0; g < 2; ++g) {
        #pragma unroll
        for (int jd = 0; jd < 4; ++jd) oacc[g][jd] = zero4;
        #pragma unroll
        for (int r = 0; r < 4; ++r) lsum[g][r] = 0.f;
    }

    const int nkt = qt * 2 + 2;
    for (int kt = 0; kt < nkt; ++kt) {
        float bb[2][4][4];
        #pragma unroll
        for (int g = 0; g < 2; ++g)
            #pragma unroll
            for (int jn = 0; jn < 4; ++jn)
                #pragma unroll
                for (int r = 0; r < 4; ++r)
                    bb[g][jn][r] = bias[((size_t)h * 2048 + q0 + g * 16 + quad * 4 + r) * 2048
                                        + kt * 64 + jn * 16 + fm];

        #pragma unroll
        for (int rep = 0; rep < 2; ++rep) {
            int idx  = rep * 256 + tid;
            int row  = idx >> 3;
            int part = idx & 7;
            *(uint4*)(Ks + row * 72 + part * 8) =
                *(const uint4*)(ks + (rowbase + kt * 64 + row) * 64 + part * 8);
            *(uint4*)(Vt + row * 72 + part * 8) =
                *(const uint4*)(vt + ((size_t)bh * 64 + row) * 2048 + kt * 64 + part * 8);
        }
        __syncthreads();

        bf16x8 kb[4][2];
        #pragma unroll
        for (int jn = 0; jn < 4; ++jn)
            #pragma unroll
            for (int c = 0; c < 2; ++c)
                kb[jn][c] = *(const bf16x8*)(Ks + (jn * 16 + fm) * 72 + c * 32 + fk);
        f32x4 sacc[2][4];
        #pragma unroll
        for (int g = 0; g < 2; ++g)
            #pragma unroll
            for (int jn = 0; jn < 4; ++jn) sacc[g][jn] = zero4;
        #pragma unroll
        for (int g = 0; g < 2; ++g)
            #pragma unroll
            for (int jn = 0; jn < 4; ++jn)
                #pragma unroll
                for (int c = 0; c < 2; ++c)
                    sacc[g][jn] = __builtin_amdgcn_mfma_f32_16x16x32_bf16(qf[g][c], kb[jn][c], sacc[g][jn], 0, 0, 0);

        #pragma unroll
        for (int g = 0; g < 2; ++g)
            #pragma unroll
            for (int jn = 0; jn < 4; ++jn)
                #pragma unroll
                for (int r = 0; r < 4; ++r) {
                    int row = q0 + g * 16 + quad * 4 + r;
                    int col = kt * 64 + jn * 16 + fm;
                    float p = exp2f(sacc[g][jn][r] * 0.18033688f + bb[g][jn][r] * 1.44269504f);
                    p = (col > row) ? 0.f : p;
                    lsum[g][r] += p;
                    Ps[w][(g * 16 + quad * 4 + r) * 72 + jn * 16 + fm] = f2bf(p);
                }

        bf16x8 vf[4][2], pf[2][2];
        #pragma unroll
        for (int jd = 0; jd < 4; ++jd)
            #pragma unroll
            for (int c = 0; c < 2; ++c)
                vf[jd][c] = *(const bf16x8*)(Vt + (jd * 16 + fm) * 72 + c * 32 + fk);
        #pragma unroll
        for (int g = 0; g < 2; ++g)
            #pragma unroll
            for (int c = 0; c < 2; ++c)
                pf[g][c] = *(const bf16x8*)(Ps[w] + (g * 16 + fm) * 72 + c * 32 + fk);
        #pragma unroll
        for (int g = 0; g < 2; ++g)
            #pragma unroll
            for (int jd = 0; jd < 4; ++jd)
                #pragma unroll
                for (int c = 0; c < 2; ++c)
                    oacc[g][jd] = __builtin_amdgcn_mfma_f32_16x16x32_bf16(pf[g][c], vf[jd][c], oacc[g][jd], 0, 0, 0);

        __syncthreads();
    }

    #pragma unroll
    for (int g = 0; g < 2; ++g)
        #pragma unroll
        for (int r = 0; r < 4; ++r) {
            float l = lsum[g][r];
            #pragma unroll
            for (int off = 1; off < 16; off <<= 1) l += __shfl_xor(l, off, 64);
            lsum[g][r] = 1.f / l;
        }

    #pragma unroll
    for (int g = 0; g < 2; ++g)
        #pragma unroll
        for (int jd = 0; jd < 4; ++jd)
            #pragma unroll
            for (int r = 0; r < 4; ++r) {
                int row = q0 + g * 16 + quad * 4 + r;
                int d   = jd * 16 + fm;
                out[((size_t)b * 2048 + row) * 1024 + h * 64 + d] = f2bf(oacc[g][jd][r] * lsum[g][r]);
            }
}

// ---------------- launcher ----------------
extern "C" void kernel_launch(void* const* d_in, const int* in_sizes, int n_in,
                              void* d_out, int out_size, void* d_ws, size_t ws_size,
                              hipStream_t stream) {
    (void)in_sizes; (void)n_in; (void)out_size; (void)ws_size;
    const float* x     = (const float*)d_in[0];
    const float* basis = (const float*)d_in[1];
    const float* sq    = (const float*)d_in[2];
    const float* sk    = (const float*)d_in[3];
    const float* sv    = (const float*)d_in[4];
    const float* so    = (const float*)d_in[5];
    const float* bias  = (const float*)d_in[6];
    float* out = (float*)d_out;

    char* ws = (char*)d_ws;
    size_t off = 0;
    auto alloc = [&](size_t bytes) { void* p = ws + off; off += bytes; return p; };
    unsigned short* x_bf  = (unsigned short*)alloc((size_t)8 << 20);
    unsigned short* Acat  = (unsigned short*)alloc((size_t)8 << 20);   // [U*sq; U*sk; U*sv; U*so]
    unsigned short* Ub    = (unsigned short*)alloc((size_t)2 << 20);
    unsigned short* Wall  = (unsigned short*)alloc((size_t)8 << 20);   // [Wq; Wk; Wv; Wo] (each symmetric)
    unsigned short* qkvb  = (unsigned short*)alloc((size_t)24 << 20);  // q,k,v head-split sections
    unsigned short* vtb   = (unsigned short*)alloc((size_t)8 << 20);
    unsigned short* attno = (unsigned short*)alloc((size_t)8 << 20);

    unsigned short* Bq  = Acat;
    unsigned short* Bk  = Acat + ((size_t)1 << 20);
    unsigned short* Bv  = Acat + ((size_t)2 << 20);
    unsigned short* Bo  = Acat + ((size_t)3 << 20);
    unsigned short* qsb = qkvb;
    unsigned short* ksb = qkvb + ((size_t)1 << 22);
    unsigned short* vsb = qkvb + ((size_t)2 << 22);
    unsigned short* Wo  = Wall + (size_t)3 * 1024 * 1024;

    k_prep<<<8192, 256, 0, stream>>>(x, basis, sq, sk, sv, so, x_bf, Bq, Bk, Bv, Bo, Ub);

    dim3 blk(256);
    // Wall = Acat @ Ub^T   (W_j = U diag(s_j) U^T, symmetric => rows usable as B^T later)
    k_gemm_n64<0><<<dim3(16, 32), blk, 0, stream>>>(Acat, Ub, Wall, 4096, 1024, 1024);
    // QKV = x @ [Wq;Wk;Wv]^T  (256x256 deep-pipeline)
    k_gemm_qkv8<<<dim3(12, 16), dim3(512), 0, stream>>>(x_bf, Wall, qkvb);
    k_transpose_v<<<dim3(16, 32), blk, 0, stream>>>(vsb, vtb);
    k_attn<<<dim3(16, 32), blk, 0, stream>>>(qsb, ksb, vtb, bias, attno);
    // out = attno @ Wo^T (f32 epilogue)
    k_gemm_n64<2><<<dim3(16, 32), blk, 0, stream>>>(attno, Wo, out, 4096, 1024, 1024);
}

// Round 3
// 506.963 us; speedup vs baseline: 1.0179x; 1.0070x over previous
//
#include <hip/hip_runtime.h>
#include <stdint.h>

#define AS1 __attribute__((address_space(1)))
#define AS3 __attribute__((address_space(3)))

typedef __bf16 bf16x8 __attribute__((ext_vector_type(8)));
typedef float f32x4 __attribute__((ext_vector_type(4)));

#if defined(__has_builtin)
#if __has_builtin(__builtin_amdgcn_global_load_lds)
#define USE_GLL 1
#else
#define USE_GLL 0
#endif
#else
#define USE_GLL 0
#endif

static __device__ __forceinline__ unsigned short f2bf(float f) {
    union { float f; uint32_t u; } v; v.f = f;
    uint32_t u = v.u + 0x7fffu + ((v.u >> 16) & 1u);
    return (unsigned short)(u >> 16);
}

// ---------------- fused elementwise prep ----------------
// blocks [0,4096): make scaled basis sections + Ub  (1M elements)
// blocks [4096,8192): x f32 -> bf16 (4M elements, float4 per thread)
__global__ void k_prep(const float* __restrict__ x, const float* __restrict__ basis,
                       const float* __restrict__ sq, const float* __restrict__ sk,
                       const float* __restrict__ sv, const float* __restrict__ so,
                       unsigned short* __restrict__ x_bf,
                       unsigned short* __restrict__ Bq, unsigned short* __restrict__ Bk,
                       unsigned short* __restrict__ Bv, unsigned short* __restrict__ Bo,
                       unsigned short* __restrict__ Ub) {
    int b = blockIdx.x;
    if (b < 4096) {
        int idx = b * 256 + threadIdx.x;
        int k = idx & 1023;
        float v = basis[idx];
        Bq[idx] = f2bf(v * sq[k]);
        Bk[idx] = f2bf(v * sk[k]);
        Bv[idx] = f2bf(v * sv[k]);
        Bo[idx] = f2bf(v * so[k]);
        Ub[idx] = f2bf(v);
    } else {
        int idx = ((b - 4096) * 256 + threadIdx.x) * 4;
        float4 v = *(const float4*)(x + idx);
        unsigned short r[4] = { f2bf(v.x), f2bf(v.y), f2bf(v.z), f2bf(v.w) };
        *(uint2*)(x_bf + idx) = *(const uint2*)r;
    }
}

// V^T: in [bh][2048][64] -> out [bh][64][2048]
__global__ void k_transpose_v(const unsigned short* __restrict__ vsb, unsigned short* __restrict__ vtb) {
    __shared__ __align__(16) unsigned short t[128 * 72];
    const int sc = blockIdx.x;   // s-chunk of 128
    const int bh = blockIdx.y;
    const int tid = threadIdx.x;
    #pragma unroll
    for (int rep = 0; rep < 4; ++rep) {
        int idx = rep * 256 + tid;          // 0..1023
        int s = idx >> 3, part = idx & 7;
        *(uint4*)(t + s * 72 + part * 8) =
            *(const uint4*)(vsb + ((size_t)bh * 2048 + sc * 128 + s) * 64 + part * 8);
    }
    __syncthreads();
    #pragma unroll
    for (int rep = 0; rep < 4; ++rep) {
        int idx = rep * 256 + tid;          // 0..1023
        int d = idx >> 4, pc = idx & 15;    // d row 0..63, 8-wide s chunk 0..15
        unsigned short tmp[8];
        #pragma unroll
        for (int j = 0; j < 8; ++j) tmp[j] = t[(pc * 8 + j) * 72 + d];
        *(uint4*)(vtb + ((size_t)bh * 64 + d) * 2048 + sc * 128 + pc * 8) = *(const uint4*)tmp;
    }
}

// ---------------- GEMM 256x192 deep-pipeline (counted vmcnt, 3-buf), QKV epilogue ----------
// C = A[4096][1024] @ B[3072][1024]^T.  Grid 16x16 = 256 blocks (exactly 1/CU).
// 512 thr (8 waves, 2M x 4N), per-wave output 128x48, BK=32, 32 K-tiles.
// Triple-buffered LDS; tile t reads buf[t%3] while staging t+2 into buf[(t+2)%3].
// Per wave per K-tile: exactly 4 GLL stage instrs (2 A + 2 B; waves 6,7 stage
// duplicate valid B rows into a scratch pad to keep per-wave vmcnt counts uniform).
// Single s_waitcnt vmcnt(4) per tile drains tile t+1 while t+2 stays in flight.
__global__ __launch_bounds__(512, 1)
void k_gemm_qkv8(const unsigned short* __restrict__ A,
                 const unsigned short* __restrict__ B,
                 unsigned short* __restrict__ qkv)
{
    // per buffer: A[256][32] = 8192 shorts, B[192][32] = 6144 shorts -> 14336 shorts
    // 3 buffers = 43008 shorts; + 2048 shorts scratch for duplicate B stages
    __shared__ __align__(16) unsigned short lds[45056];   // 88 KiB

    const int tid  = threadIdx.x;
    const int lane = tid & 63;
    const int w    = tid >> 6;
    const int wm   = w & 1;     // M-half (128 rows)
    const int wn   = w >> 1;    // N-quarter (48 cols)
    const int fm   = lane & 15;
    const int quad = lane >> 4;
    const int K    = 1024;
    const int NT   = 32;

    // XCD-aware bijective swizzle over exactly 256 blocks (32 contiguous per XCD)
    int bid  = blockIdx.y * 16 + blockIdx.x;
    int sbid = (bid & 7) * 32 + (bid >> 3);
    const int bm = sbid >> 4;   // 0..15  (256-row tile)
    const int bn = sbid & 15;   // 0..15  (192-row tile of B)

    // staging: one GLL instr = 64 lanes x 16B = 16 rows of 32 shorts.
    // wave w stages A rows [32w, 32w+32) via 2 instrs (h=0,1 -> +16 rows).
    // wave w<6 stages B rows [32w, 32w+32); waves 6,7 duplicate B rows [0,64) -> scratch.
    const int arow = w * 32 + (lane >> 2);
    const int brow = ((w < 6) ? w * 32 : (w - 6) * 32) + (lane >> 2);
    const int sg   = (lane & 3) * 8;
    const unsigned short* gA = A + ((size_t)(bm * 256) + arow) * K + sg;
    const unsigned short* gB = B + ((size_t)(bn * 192) + brow) * K + sg;

#define ADST(tt, h) (lds + ((tt) % 3) * 14336 + w * 1024 + (h) * 512)
#define BDST(tt, h) ((w < 6) ? (lds + ((tt) % 3) * 14336 + 8192 + w * 1024 + (h) * 512) \
                             : (lds + 43008 + (w - 6) * 1024 + (h) * 512))
#define STAGE_A(tt, h) __builtin_amdgcn_global_load_lds( \
        (const void AS1*)(gA + (size_t)(h) * 16 * 1024 + (size_t)(tt) * 32), \
        (void AS3*)ADST(tt, h), 16, 0, 0)
#define STAGE_B(tt, h) __builtin_amdgcn_global_load_lds( \
        (const void AS1*)(gB + (size_t)(h) * 16 * 1024 + (size_t)(tt) * 32), \
        (void AS3*)BDST(tt, h), 16, 0, 0)

    f32x4 zero4 = {0.f, 0.f, 0.f, 0.f};
    f32x4 acc[8][3];
    #pragma unroll
    for (int i = 0; i < 8; ++i)
        #pragma unroll
        for (int j = 0; j < 3; ++j) acc[i][j] = zero4;

    // prologue: stage tiles 0 and 1 (4 instrs each per wave), drain tile 0 only
    STAGE_A(0, 0); STAGE_A(0, 1); STAGE_B(0, 0); STAGE_B(0, 1);
    STAGE_A(1, 0); STAGE_A(1, 1); STAGE_B(1, 0); STAGE_B(1, 1);
    asm volatile("s_waitcnt vmcnt(4)" ::: "memory");
    __builtin_amdgcn_s_barrier();

    for (int t = 0; t < NT; ++t) {
        const unsigned short* buf  = lds + (t % 3) * 14336;
        const unsigned short* bufB = buf + 8192;

        // ---- phase A: B-frags + A-frags 0-3, stage A-halves of t+2 ----
        bf16x8 bfr[3], af[4];
        #pragma unroll
        for (int j = 0; j < 3; ++j)
            bfr[j] = *(const bf16x8*)(bufB + (wn * 48 + j * 16 + fm) * 32 + quad * 8);
        #pragma unroll
        for (int i = 0; i < 4; ++i)
            af[i] = *(const bf16x8*)(buf + (wm * 128 + i * 16 + fm) * 32 + quad * 8);
        if (t + 2 < NT) { STAGE_A(t + 2, 0); STAGE_A(t + 2, 1); }
        __builtin_amdgcn_s_barrier();
        asm volatile("s_waitcnt lgkmcnt(0)" ::: "memory");
        __builtin_amdgcn_s_setprio(1);
        #pragma unroll
        for (int i = 0; i < 4; ++i)
            #pragma unroll
            for (int j = 0; j < 3; ++j)
                acc[i][j] = __builtin_amdgcn_mfma_f32_16x16x32_bf16(af[i], bfr[j], acc[i][j], 0, 0, 0);
        __builtin_amdgcn_s_setprio(0);
        __builtin_amdgcn_s_barrier();

        // ---- phase B: A-frags 4-7 (B reused in regs), stage B-halves of t+2 ----
        bf16x8 af2[4];
        #pragma unroll
        for (int i = 0; i < 4; ++i)
            af2[i] = *(const bf16x8*)(buf + (wm * 128 + 64 + i * 16 + fm) * 32 + quad * 8);
        if (t + 2 < NT) { STAGE_B(t + 2, 0); STAGE_B(t + 2, 1); }
        // counted drain: outstanding = 4 (tile t+1) + 4 (tile t+2) -> wait down to 4
        if (t < NT - 2)       asm volatile("s_waitcnt vmcnt(4)" ::: "memory");
        else if (t == NT - 2) asm volatile("s_waitcnt vmcnt(0)" ::: "memory");
        __builtin_amdgcn_s_barrier();
        asm volatile("s_waitcnt lgkmcnt(0)" ::: "memory");
        __builtin_amdgcn_s_setprio(1);
        #pragma unroll
        for (int i = 0; i < 4; ++i)
            #pragma unroll
            for (int j = 0; j < 3; ++j)
                acc[i + 4][j] = __builtin_amdgcn_mfma_f32_16x16x32_bf16(af2[i], bfr[j], acc[i + 4][j], 0, 0, 0);
        __builtin_amdgcn_s_setprio(0);
        __builtin_amdgcn_s_barrier();
    }
#undef STAGE_A
#undef STAGE_B
#undef ADST
#undef BDST

    // epilogue: head-split scatter into q/k/v sections
    #pragma unroll
    for (int i = 0; i < 8; ++i)
        #pragma unroll
        for (int j = 0; j < 3; ++j)
            #pragma unroll
            for (int r = 0; r < 4; ++r) {
                int row = bm * 256 + wm * 128 + i * 16 + quad * 4 + r;
                int col = bn * 192 + wn * 48 + j * 16 + fm;
                int sec = col >> 10, cc = col & 1023;
                int bb = row >> 11, s = row & 2047;
                int hh = cc >> 6,  d = cc & 63;
                qkv[((size_t)sec << 22) + (((size_t)(bb * 16 + hh)) * 2048 + s) * 64 + d] = f2bf(acc[i][j][r]);
            }
}

// ---------------- GEMM 128Mx64N tiles ----------------
#define BK 32
// EPI: 0 = bf16 row-major, 2 = f32 row-major
template<int EPI>
__global__ __launch_bounds__(256, 2)
void k_gemm_n64(const unsigned short* __restrict__ A,
                const unsigned short* __restrict__ B,
                void* __restrict__ Cout,
                int M, int N, int K)
{
    __shared__ __align__(16) unsigned short As[128 * BK];
    __shared__ __align__(16) unsigned short Bs[64 * BK];

    const int tid  = threadIdx.x;
    const int lane = tid & 63;
    const int w    = tid >> 6;
    const int wm   = w & 1;
    const int wn   = w >> 1;
    const int bm   = blockIdx.y;
    const int bn   = blockIdx.x;
    const int fm   = lane & 15;
    const int quad = lane >> 4;
    const int fk   = quad * 8;
    const int srow = lane >> 2;
    const int spart= lane & 3;

    f32x4 zero4 = {0.f, 0.f, 0.f, 0.f};
    f32x4 acc[4][2];
    #pragma unroll
    for (int i = 0; i < 4; ++i)
        #pragma unroll
        for (int j = 0; j < 2; ++j) acc[i][j] = zero4;

    for (int k0 = 0; k0 < K; k0 += BK) {
        #pragma unroll
        for (int t = 0; t < 2; ++t) {
            int row = w * 32 + t * 16 + srow;
            const unsigned short* ga = A + (size_t)(bm * 128 + row) * K + k0 + spart * 8;
#if USE_GLL
            __builtin_amdgcn_global_load_lds((const void AS1*)ga, (void AS3*)(As + w * 1024 + t * 512), 16, 0, 0);
#else
            *(uint4*)(As + w * 1024 + t * 512 + lane * 8) = *(const uint4*)ga;
#endif
        }
        {
            const unsigned short* gb = B + (size_t)(bn * 64 + w * 16 + srow) * K + k0 + spart * 8;
#if USE_GLL
            __builtin_amdgcn_global_load_lds((const void AS1*)gb, (void AS3*)(Bs + w * 512), 16, 0, 0);
#else
            *(uint4*)(Bs + w * 512 + lane * 8) = *(const uint4*)gb;
#endif
        }
        __syncthreads();
        bf16x8 af[4], bfr[2];
        #pragma unroll
        for (int i = 0; i < 4; ++i) af[i] = *(const bf16x8*)(As + (wm * 64 + i * 16 + fm) * BK + fk);
        #pragma unroll
        for (int j = 0; j < 2; ++j) bfr[j] = *(const bf16x8*)(Bs + (wn * 32 + j * 16 + fm) * BK + fk);
        #pragma unroll
        for (int i = 0; i < 4; ++i)
            #pragma unroll
            for (int j = 0; j < 2; ++j)
                acc[i][j] = __builtin_amdgcn_mfma_f32_16x16x32_bf16(af[i], bfr[j], acc[i][j], 0, 0, 0);
        __syncthreads();
    }

    #pragma unroll
    for (int i = 0; i < 4; ++i)
        #pragma unroll
        for (int j = 0; j < 2; ++j)
            #pragma unroll
            for (int r = 0; r < 4; ++r) {
                int row = bm * 128 + wm * 64 + i * 16 + quad * 4 + r;
                int col = bn * 64 + wn * 32 + j * 16 + fm;
                if (EPI == 0) ((unsigned short*)Cout)[(size_t)row * N + col] = f2bf(acc[i][j][r]);
                else          ((float*)Cout)[(size_t)row * N + col] = acc[i][j][r];
            }
}

// ---------------- flash attention: 128 q-rows/block (32 per wave), b-paired bias reuse ------
__global__ __launch_bounds__(256, 2)
void k_attn(const unsigned short* __restrict__ qs, const unsigned short* __restrict__ ks,
            const unsigned short* __restrict__ vt, const float* __restrict__ bias,
            unsigned short* __restrict__ out)
{
    const int qt = 15 - blockIdx.x;  // heavy (long-k) blocks dispatched first
    const int by = blockIdx.y;       // 0..31
    const int h  = by >> 1;
    const int b  = by & 1;
    const int bh = b * 16 + h;
    const size_t rowbase = (size_t)bh * 2048;

    const int tid  = threadIdx.x;
    const int lane = tid & 63;
    const int w    = tid >> 6;
    const int fm   = lane & 15;
    const int quad = lane >> 4;
    const int fk   = quad * 8;

    __shared__ __align__(16) unsigned short Ks[64 * 72];       // [key][d]
    __shared__ __align__(16) unsigned short Vt[64 * 72];       // [d][key]
    __shared__ __align__(16) unsigned short Ps[4][32 * 72];    // per-wave P (32 q-rows)

    const int q0 = qt * 128 + w * 32;   // wave's first q-row; groups at q0, q0+16

    bf16x8 qf[2][2];
    #pragma unroll
    for (int g = 0; g < 2; ++g)
        #pragma unroll
        for (int c = 0; c < 2; ++c)
            qf[g][c] = *(const bf16x8*)(qs + (rowbase + q0 + g * 16 + fm) * 64 + c * 32 + fk);

    f32x4 zero4 = {0.f, 0.f, 0.f, 0.f};
    f32x4 oacc[2][4];
    float lsum[2][4];
    #pragma unroll
    for (int g = 0; g < 2; ++g) {
        #pragma unroll
        for (int jd = 0; jd < 4; ++jd) oacc[g][jd] = zero4;
        #pragma unroll
        for (int r = 0; r < 4; ++r) lsum[g][r] = 0.f;
    }

    const int nkt = qt * 2 + 2;
    for (int kt = 0; kt < nkt; ++kt) {
        float bb[2][4][4];
        #pragma unroll
        for (int g = 0; g < 2; ++g)
            #pragma unroll
            for (int jn = 0; jn < 4; ++jn)
                #pragma unroll
                for (int r = 0; r < 4; ++r)
                    bb[g][jn][r] = bias[((size_t)h * 2048 + q0 + g * 16 + quad * 4 + r) * 2048
                                        + kt * 64 + jn * 16 + fm];

        #pragma unroll
        for (int rep = 0; rep < 2; ++rep) {
            int idx  = rep * 256 + tid;
            int row  = idx >> 3;
            int part = idx & 7;
            *(uint4*)(Ks + row * 72 + part * 8) =
                *(const uint4*)(ks + (rowbase + kt * 64 + row) * 64 + part * 8);
            *(uint4*)(Vt + row * 72 + part * 8) =
                *(const uint4*)(vt + ((size_t)bh * 64 + row) * 2048 + kt * 64 + part * 8);
        }
        __syncthreads();

        bf16x8 kb[4][2];
        #pragma unroll
        for (int jn = 0; jn < 4; ++jn)
            #pragma unroll
            for (int c = 0; c < 2; ++c)
                kb[jn][c] = *(const bf16x8*)(Ks + (jn * 16 + fm) * 72 + c * 32 + fk);
        f32x4 sacc[2][4];
        #pragma unroll
        for (int g = 0; g < 2; ++g)
            #pragma unroll
            for (int jn = 0; jn < 4; ++jn) sacc[g][jn] = zero4;
        #pragma unroll
        for (int g = 0; g < 2; ++g)
            #pragma unroll
            for (int jn = 0; jn < 4; ++jn)
                #pragma unroll
                for (int c = 0; c < 2; ++c)
                    sacc[g][jn] = __builtin_amdgcn_mfma_f32_16x16x32_bf16(qf[g][c], kb[jn][c], sacc[g][jn], 0, 0, 0);

        #pragma unroll
        for (int g = 0; g < 2; ++g)
            #pragma unroll
            for (int jn = 0; jn < 4; ++jn)
                #pragma unroll
                for (int r = 0; r < 4; ++r) {
                    int row = q0 + g * 16 + quad * 4 + r;
                    int col = kt * 64 + jn * 16 + fm;
                    float p = exp2f(sacc[g][jn][r] * 0.18033688f + bb[g][jn][r] * 1.44269504f);
                    p = (col > row) ? 0.f : p;
                    lsum[g][r] += p;
                    Ps[w][(g * 16 + quad * 4 + r) * 72 + jn * 16 + fm] = f2bf(p);
                }

        bf16x8 vf[4][2], pf[2][2];
        #pragma unroll
        for (int jd = 0; jd < 4; ++jd)
            #pragma unroll
            for (int c = 0; c < 2; ++c)
                vf[jd][c] = *(const bf16x8*)(Vt + (jd * 16 + fm) * 72 + c * 32 + fk);
        #pragma unroll
        for (int g = 0; g < 2; ++g)
            #pragma unroll
            for (int c = 0; c < 2; ++c)
                pf[g][c] = *(const bf16x8*)(Ps[w] + (g * 16 + fm) * 72 + c * 32 + fk);
        #pragma unroll
        for (int g = 0; g < 2; ++g)
            #pragma unroll
            for (int jd = 0; jd < 4; ++jd)
                #pragma unroll
                for (int c = 0; c < 2; ++c)
                    oacc[g][jd] = __builtin_amdgcn_mfma_f32_16x16x32_bf16(pf[g][c], vf[jd][c], oacc[g][jd], 0, 0, 0);

        __syncthreads();
    }

    #pragma unroll
    for (int g = 0; g < 2; ++g)
        #pragma unroll
        for (int r = 0; r < 4; ++r) {
            float l = lsum[g][r];
            #pragma unroll
            for (int off = 1; off < 16; off <<= 1) l += __shfl_xor(l, off, 64);
            lsum[g][r] = 1.f / l;
        }

    #pragma unroll
    for (int g = 0; g < 2; ++g)
        #pragma unroll
        for (int jd = 0; jd < 4; ++jd)
            #pragma unroll
            for (int r = 0; r < 4; ++r) {
                int row = q0 + g * 16 + quad * 4 + r;
                int d   = jd * 16 + fm;
                out[((size_t)b * 2048 + row) * 1024 + h * 64 + d] = f2bf(oacc[g][jd][r] * lsum[g][r]);
            }
}

// ---------------- launcher ----------------
extern "C" void kernel_launch(void* const* d_in, const int* in_sizes, int n_in,
                              void* d_out, int out_size, void* d_ws, size_t ws_size,
                              hipStream_t stream) {
    (void)in_sizes; (void)n_in; (void)out_size; (void)ws_size;
    const float* x     = (const float*)d_in[0];
    const float* basis = (const float*)d_in[1];
    const float* sq    = (const float*)d_in[2];
    const float* sk    = (const float*)d_in[3];
    const float* sv    = (const float*)d_in[4];
    const float* so    = (const float*)d_in[5];
    const float* bias  = (const float*)d_in[6];
    float* out = (float*)d_out;

    char* ws = (char*)d_ws;
    size_t off = 0;
    auto alloc = [&](size_t bytes) { void* p = ws + off; off += bytes; return p; };
    unsigned short* x_bf  = (unsigned short*)alloc((size_t)8 << 20);
    unsigned short* Acat  = (unsigned short*)alloc((size_t)8 << 20);   // [U*sq; U*sk; U*sv; U*so]
    unsigned short* Ub    = (unsigned short*)alloc((size_t)2 << 20);
    unsigned short* Wall  = (unsigned short*)alloc((size_t)8 << 20);   // [Wq; Wk; Wv; Wo] (each symmetric)
    unsigned short* qkvb  = (unsigned short*)alloc((size_t)24 << 20);  // q,k,v head-split sections
    unsigned short* vtb   = (unsigned short*)alloc((size_t)8 << 20);
    unsigned short* attno = (unsigned short*)alloc((size_t)8 << 20);

    unsigned short* Bq  = Acat;
    unsigned short* Bk  = Acat + ((size_t)1 << 20);
    unsigned short* Bv  = Acat + ((size_t)2 << 20);
    unsigned short* Bo  = Acat + ((size_t)3 << 20);
    unsigned short* qsb = qkvb;
    unsigned short* ksb = qkvb + ((size_t)1 << 22);
    unsigned short* vsb = qkvb + ((size_t)2 << 22);
    unsigned short* Wo  = Wall + (size_t)3 * 1024 * 1024;

    k_prep<<<8192, 256, 0, stream>>>(x, basis, sq, sk, sv, so, x_bf, Bq, Bk, Bv, Bo, Ub);

    dim3 blk(256);
    // Wall = Acat @ Ub^T   (W_j = U diag(s_j) U^T, symmetric => rows usable as B^T later)
    k_gemm_n64<0><<<dim3(16, 32), blk, 0, stream>>>(Acat, Ub, Wall, 4096, 1024, 1024);
    // QKV = x @ [Wq;Wk;Wv]^T  (256x192 deep-pipeline, 256 blocks = 1/CU)
    k_gemm_qkv8<<<dim3(16, 16), dim3(512), 0, stream>>>(x_bf, Wall, qkvb);
    k_transpose_v<<<dim3(16, 32), blk, 0, stream>>>(vsb, vtb);
    k_attn<<<dim3(16, 32), blk, 0, stream>>>(qsb, ksb, vtb, bias, attno);
    // out = attno @ Wo^T (f32 epilogue)
    k_gemm_n64<2><<<dim3(16, 32), blk, 0, stream>>>(attno, Wo, out, 4096, 1024, 1024);
}